// Round 9
// baseline (296.587 us; speedup 1.0000x reference)
//
#include <hip/hip_runtime.h>

// ConvLSTM1D fused scan for MI355X — f32 I/O, bf16 MFMA.
// Round 9: round-6 body (scalar pointwise = measured best) at LTILE=32 with
// 1024 blocks -> 4 blocks/CU from ACTUAL resources (VGPR ~104 <= 128), not
// launch-bounds (r7's bound=4 strangled the allocator to 64 VGPR and spilled).
// Slot-1 LDS reads guarded (r7 read past the LDS block); x prefetch predicated
// on q<2 (only those lanes consume it -> halves x VMEM traffic).
// Halo-tile trick: block owns j-range [j0, j0+32); recurrent conv reads h[j+1]
// only, so a right halo that starts at +49 rows and shrinks by 1 per step makes
// every block's 50-step scan fully independent (no grid sync).

#define TT 50
#define LTILE 32
#define ROWS 97    // max nmt = ceil(81/16) = 6 -> max row read = 5*16+15+1 = 96
#define HSTR 40    // h row stride (shorts); mult of 8 -> 16B-aligned ds_read_b128

typedef __attribute__((ext_vector_type(8))) short short8;
typedef __attribute__((ext_vector_type(4))) float floatx4;

__device__ __forceinline__ unsigned short f2b_rne(float f) {
  union { float f; unsigned u; } v; v.f = f;
  unsigned r = v.u + 0x7FFFu + ((v.u >> 16) & 1u);
  return (unsigned short)(r >> 16);
}
__device__ __forceinline__ unsigned short f2b_trunc(float f) {
  union { float f; unsigned u; } v; v.f = f;
  return (unsigned short)(v.u >> 16);
}
__device__ __forceinline__ float hsig(float x) {
  return __builtin_amdgcn_fmed3f(__builtin_fmaf(0.2f, x, 0.5f), 0.0f, 1.0f);
}
__device__ __forceinline__ float ftanh(float x) {
  float e = __expf(2.0f * x);
  return 1.0f - 2.0f * __builtin_amdgcn_rcpf(e + 1.0f);
}

__global__ __launch_bounds__(256, 2)
void convlstm_scan(const float* __restrict__ xs,   // x [32][50][2048][8] f32
                   const float* __restrict__ ks,   // kernel [2][8][128] f32
                   const float* __restrict__ rks,  // rec_kernel [2][32][128] f32
                   const float* __restrict__ bs,   // bias [128] f32
                   const float* __restrict__ dws,  // dense_w [32768] f32
                   float* __restrict__ acc_out) {  // [32] f32 accumulators
  __shared__ short hbH[2][ROWS * HSTR];   // h (bf16), double-buffered

  const int tid  = threadIdx.x;
  const int b    = blockIdx.x >> 5;
  const int j0   = (blockIdx.x & 31) * LTILE;
  const int wave = tid >> 6;
  const int lane = tid & 63;
  const int q    = lane >> 4;
  const int f0   = lane & 15;

  for (int e = tid; e < ROWS * HSTR; e += 256)
    ((int*)hbH)[e] = 0;

  // ---- B fragments in registers, GATE-PAIR PERMUTED columns:
  // tile n = 2g+p, col f0  <->  oc = g*32 + 2*f0 + p   (g = gate, p = pair)
  // => lane f0's two outputs per row are adjacent h-cols 2f0, 2f0+1.
  short8 Bwh0[8], Bwh1[8], Bxw[8];
#pragma unroll
  for (int n = 0; n < 8; ++n) {
    const int oc = (n >> 1) * 32 + 2 * f0 + (n & 1);
    short8 th;
#pragma unroll
    for (int j = 0; j < 8; ++j)
      th[j] = (short)f2b_rne(rks[(q * 8 + j) * 128 + oc]);
    Bwh0[n] = th;
#pragma unroll
    for (int j = 0; j < 8; ++j)
      th[j] = (short)f2b_rne(rks[(32 + q * 8 + j) * 128 + oc]);
    Bwh1[n] = th;
    // x-conv B: k rows 0..7 = tap0 k_hi, 8..15 = tap1 k_hi (paired with x_hi),
    // row 16 = bias (ax carries 1.0 there), rows 17..31 = 0.
    short8 tx = {0, 0, 0, 0, 0, 0, 0, 0};
    if (q < 2) {
#pragma unroll
      for (int j = 0; j < 8; ++j)
        tx[j] = (short)f2b_rne(ks[(q * 8 + j) * 128 + oc]);
    } else if (q == 2) {
      tx[0] = (short)f2b_rne(bs[oc]);
    }
    Bxw[n] = tx;
  }

  // ax constant part: lane (q=2, elem 0) = bf16 1.0 (bias marker), else 0.
  short8 axc = {0, 0, 0, 0, 0, 0, 0, 0};
  if (q == 2) axc[0] = (short)0x3F80;

  const floatx4 zero4 = {0.0f, 0.0f, 0.0f, 0.0f};

  float cst[2][8];   // c-state, MFMA C-layout: [m-slot][p*4 + r]
#pragma unroll
  for (int s = 0; s < 2; ++s)
#pragma unroll
    for (int i = 0; i < 8; ++i) cst[s][i] = 0.0f;

  // ---- hoisted x pointers (row clamp is t-invariant); advance 16384 fl/step.
  // Only q<2 lanes consume px; predicate their loads (exec-masked).
  const float* xptr[2];
  floatx4 px0[2], px1[2];
#pragma unroll
  for (int s = 0; s < 2; ++s) {
    const int jr = (wave + 4 * s) * 16 + f0;
    const int jm = min(j0 + jr, 1023);
    xptr[s] = xs + (size_t)b * TT * (2048 * 8) + (size_t)(2 * jm + (q & 1)) * 8;
  }
  if (q < 2) {
    px0[0] = *(const floatx4*)xptr[0];
    px1[0] = *(const floatx4*)(xptr[0] + 4);
    if (wave < 2) {   // slot1 only ever active for waves 0,1 (nmt <= 6)
      px0[1] = *(const floatx4*)xptr[1];
      px1[1] = *(const floatx4*)(xptr[1] + 4);
    }
  }

  const int maxrows = 1024 - j0;
  float part = 0.0f;                        // fused Dense(1) partial
  __syncthreads();

  for (int t = 0; t < TT; ++t) {
    const short* curH = hbH[t & 1];
    short* nxtH = hbH[(t & 1) ^ 1];
    int rows = LTILE + (TT - 1) - t;          // halo shrinks 1/step
    if (rows > maxrows) rows = maxrows;
    const int nmt = (rows + 15) >> 4;         // 2..6
    const int act0 = wave < nmt;              // wave-uniform slot guards
    const int act1 = (wave + 4) < nmt;
    const int last = (t == TT - 1);

    // 1) Front-load a-frag LDS reads. Slot0 rows <= 64 always in-bounds;
    //    slot1 guarded (when active: max row = 5*16+15+1 = 96 = ROWS-1).
    short8 a0h[2], a1h[2];
    {
      const int jr = wave * 16 + f0;
      a0h[0] = *(const short8*)&curH[jr * HSTR + q * 8];
      a1h[0] = *(const short8*)&curH[(jr + 1) * HSTR + q * 8];
    }
    if (act1) {
      const int jr = (wave + 4) * 16 + f0;
      a0h[1] = *(const short8*)&curH[jr * HSTR + q * 8];
      a1h[1] = *(const short8*)&curH[(jr + 1) * HSTR + q * 8];
    }

    // 2) Build ax (x_hi) from registers prefetched last step.
    // k = q*8+j: q0 -> hi(x[2J][j]), q1 -> hi(x[2J+1][j]), q2 -> bias marker.
    short8 ax[2];
#pragma unroll
    for (int s = 0; s < 2; ++s) {
      ax[s] = axc;
      if (q < 2) {
        floatx4 x0 = px0[s], x1 = px1[s];
#pragma unroll
        for (int jj = 0; jj < 4; ++jj) ax[s][jj] = (short)f2b_trunc(x0[jj]);
#pragma unroll
        for (int jj = 0; jj < 4; ++jj) ax[s][4 + jj] = (short)f2b_trunc(x1[jj]);
      }
    }

    // 3) Next-step x prefetch: constant-stride bump, predicated (overlaps MFMA).
    if (!last) {
      xptr[0] += 2048 * 8;
      xptr[1] += 2048 * 8;
      if (q < 2) {
        px0[0] = *(const floatx4*)xptr[0];
        px1[0] = *(const floatx4*)(xptr[0] + 4);
        if (wave < 2) {
          px0[1] = *(const floatx4*)xptr[1];
          px1[1] = *(const floatx4*)(xptr[1] + 4);
        }
      }
    }

    // 4) Per-slot MFMA + pointwise.
#pragma unroll
    for (int s = 0; s < 2; ++s) {
      if (s == 0 ? !act0 : !act1) continue;
      const int m = wave + 4 * s;

      floatx4 acc[8];
      // ax first: operands in registers, C = zero4; issues while ds_reads land.
#pragma unroll
      for (int n = 0; n < 8; ++n)
        acc[n] = __builtin_amdgcn_mfma_f32_16x16x32_bf16(ax[s], Bxw[n], zero4, 0, 0, 0);
#pragma unroll
      for (int n = 0; n < 8; ++n)
        acc[n] = __builtin_amdgcn_mfma_f32_16x16x32_bf16(a0h[s], Bwh0[n], acc[n], 0, 0, 0);
#pragma unroll
      for (int n = 0; n < 8; ++n)
        acc[n] = __builtin_amdgcn_mfma_f32_16x16x32_bf16(a1h[s], Bwh1[n], acc[n], 0, 0, 0);

      // Pointwise LSTM. D[m-row = q*4+r][tile n, col f0 -> h-col 2f0 + (n&1)].
      const int jw = m * 16 + q * 4;
#pragma unroll
      for (int r = 0; r < 4; ++r) {
        float hv2[2];
#pragma unroll
        for (int p = 0; p < 2; ++p) {
          float zi = acc[0 + p][r], zf = acc[2 + p][r];
          float zc = acc[4 + p][r], zo = acc[6 + p][r];
          float ig = hsig(zi), fg = hsig(zf), og = hsig(zo);
          float cs = cst[s][p * 4 + r];
          float cn = __builtin_fmaf(fg, cs, ig * ftanh(zc));
          cst[s][p * 4 + r] = cn;
          hv2[p] = og * ftanh(cn);
        }
        if (!last) {
          unsigned pk = (unsigned)f2b_rne(hv2[0]) |
                        ((unsigned)f2b_rne(hv2[1]) << 16);
          *(unsigned*)&nxtH[(jw + r) * HSTR + 2 * f0] = pk;
        } else {
          // t=49: nmt=2 -> waves 0,1 slot0; rows jw+r cover exactly [0,32).
          const int di = (j0 + jw + r) * 32 + 2 * f0;
          part = __builtin_fmaf(hv2[0], dws[di],
                 __builtin_fmaf(hv2[1], dws[di + 1], part));
        }
      }
    }
    __syncthreads();
  }

  // ---- reduce fused-dense partials
#pragma unroll
  for (int off = 32; off > 0; off >>= 1) part += __shfl_down(part, off);
  if (lane == 0) atomicAdd(&acc_out[b], part);
}

__global__ void init_acc(float* ws) {
  if (threadIdx.x < 32) ws[threadIdx.x] = 0.0f;
}

__global__ void finalize(const float* __restrict__ ws,
                         const float* __restrict__ db,
                         float* __restrict__ out) {
  int i = threadIdx.x;
  if (i < 32) out[i] = ws[i] + db[0];
}

extern "C" void kernel_launch(void* const* d_in, const int* in_sizes, int n_in,
                              void* d_out, int out_size, void* d_ws, size_t ws_size,
                              hipStream_t stream) {
  const float* x  = (const float*)d_in[0];
  const float* k  = (const float*)d_in[1];
  const float* rk = (const float*)d_in[2];
  const float* bi = (const float*)d_in[3];
  const float* dw = (const float*)d_in[4];
  const float* db = (const float*)d_in[5];
  float* ws = (float*)d_ws;
  float* out = (float*)d_out;

  hipLaunchKernelGGL(init_acc, dim3(1), dim3(64), 0, stream, ws);
  hipLaunchKernelGGL(convlstm_scan, dim3(1024), dim3(256), 0, stream,
                     x, k, rk, bi, dw, ws);
  hipLaunchKernelGGL(finalize, dim3(1), dim3(64), 0, stream, ws, db, out);
}